// Round 15
// baseline (120.298 us; speedup 1.0000x reference)
//
#include <hip/hip_runtime.h>
#include <hip/hip_bf16.h>

#define NUM_HEADS 16
#define HEAD_DIM 64
#define DIM 1024
#define NTOK 2048
#define MTOT 4096

typedef __attribute__((ext_vector_type(8))) short bf16x8;
typedef __attribute__((ext_vector_type(4))) float f32x4;
typedef __attribute__((ext_vector_type(8))) float f32x8;
typedef __attribute__((ext_vector_type(16))) float f32x16;
typedef __attribute__((ext_vector_type(2))) unsigned int uint2v;

__device__ __forceinline__ unsigned short f2bf(float f) {
    union { __hip_bfloat16 h; unsigned short u; } c;
    c.h = __float2bfloat16(f);
    return c.u;
}

__device__ __forceinline__ unsigned int packbf(float lo, float hi) {
    union { unsigned short us[2]; unsigned int u; } p;
    p.us[0] = f2bf(lo); p.us[1] = f2bf(hi);
    return p.u;
}

__device__ __forceinline__ void plswap(unsigned int &a, unsigned int &b) {
#if __has_builtin(__builtin_amdgcn_permlane32_swap)
    uint2v r = __builtin_amdgcn_permlane32_swap(a, b, false, false);
    a = r[0]; b = r[1];
#else
    unsigned int pa = (unsigned int)__shfl_xor((int)a, 32);
    unsigned int pb = (unsigned int)__shfl_xor((int)b, 32);
    bool hi = (threadIdx.x & 32) != 0;
    unsigned int an = hi ? pb : a;
    unsigned int bn = hi ? b : pa;
    a = an; b = bn;
#endif
}

// vectorized 16-lane-local sum (enables v_pk_add_f32)
__device__ __forceinline__ float sum16v(f32x16 S) {
    f32x8 lo = __builtin_shufflevector(S, S, 0, 1, 2, 3, 4, 5, 6, 7);
    f32x8 hi = __builtin_shufflevector(S, S, 8, 9, 10, 11, 12, 13, 14, 15);
    f32x8 s8 = lo + hi;
    f32x4 a4 = __builtin_shufflevector(s8, s8, 0, 1, 2, 3) +
               __builtin_shufflevector(s8, s8, 4, 5, 6, 7);
    return (a4[0] + a4[1]) + (a4[2] + a4[3]);
}

__device__ __forceinline__ void gload16(const unsigned short* g, unsigned short* l) {
    __builtin_amdgcn_global_load_lds(
        (const __attribute__((address_space(1))) void*)g,
        (__attribute__((address_space(3))) void*)l, 16, 0, 0);
}

// ---------------- Kernel 0: fused fp32 -> bf16 convert ----------------
__global__ __launch_bounds__(256) void k_conv3(
    const float* __restrict__ s0, unsigned short* __restrict__ d0, int n0,
    const float* __restrict__ s1, unsigned short* __restrict__ d1, int n1,
    const float* __restrict__ s2, unsigned short* __restrict__ d2, int n2)
{
    int blk = blockIdx.x;
    int b0 = n0 >> 11, b1 = n1 >> 11;
    const float* s; unsigned short* d; int i;
    if (blk < b0)            { s = s0; d = d0; i = blk; }
    else if (blk < b0 + b1)  { s = s1; d = d1; i = blk - b0; }
    else                     { s = s2; d = d2; i = blk - b0 - b1; }
    int idx = (i * 256 + threadIdx.x) * 8;
    float4 a = *(const float4*)(s + idx);
    float4 b = *(const float4*)(s + idx + 4);
    union { unsigned short us[8]; uint4 u4; } p;
    p.us[0] = f2bf(a.x); p.us[1] = f2bf(a.y); p.us[2] = f2bf(a.z); p.us[3] = f2bf(a.w);
    p.us[4] = f2bf(b.x); p.us[5] = f2bf(b.y); p.us[6] = f2bf(b.z); p.us[7] = f2bf(b.w);
    *(uint4*)(d + idx) = p.u4;
}

// ---------------- Kernel 1: QKV GEMM (32x32 MFMA) + bias + RoPE + layout ----------------
__global__ __launch_bounds__(256) void k_gemm_qkv(
    const unsigned short* __restrict__ xb, const unsigned short* __restrict__ wb,
    const float* __restrict__ bias, const float* __restrict__ rcos,
    const float* __restrict__ rsin,
    unsigned short* __restrict__ qb, unsigned short* __restrict__ kb,
    unsigned short* __restrict__ vtb)
{
    __shared__ __align__(16) unsigned char smem[34816];
    unsigned short* As = (unsigned short*)smem;
    unsigned short* Bs = (unsigned short*)(smem + 16384);

    const int tid  = threadIdx.x;
    const int lane = tid & 63;
    const int wid  = tid >> 6;
    const int lc   = lane & 31;
    const int hi   = lane >> 5;
    const int wm   = (wid >> 1) * 64;
    const int wn   = (wid & 1) * 64;
    const int m0   = blockIdx.y * 128;
    const int n0   = blockIdx.x * 128;

    const f32x16 z16 = {0.f,0.f,0.f,0.f, 0.f,0.f,0.f,0.f, 0.f,0.f,0.f,0.f, 0.f,0.f,0.f,0.f};
    f32x16 acc[2][2];
    acc[0][0] = z16; acc[0][1] = z16; acc[1][0] = z16; acc[1][1] = z16;

    for (int k0 = 0; k0 < DIM; k0 += 64) {
        #pragma unroll
        for (int it = 0; it < 4; ++it) {
            int p   = tid + it * 256;
            int row = p >> 3;
            int c   = (p & 7) ^ (row & 7);
            gload16(xb + (size_t)(m0 + row) * DIM + k0 + c*8, As + p*8);
            gload16(wb + (size_t)(n0 + row) * DIM + k0 + c*8, Bs + p*8);
        }
        __syncthreads();
        #pragma unroll
        for (int kk = 0; kk < 4; ++kk) {
            bf16x8 af[2], bfr[2];
            #pragma unroll
            for (int i = 0; i < 2; ++i) {
                int row = wm + i*32 + lc;
                af[i] = *(const bf16x8*)(As + row*64 + (((kk*2 + hi) ^ (row & 7)) << 3));
            }
            #pragma unroll
            for (int j = 0; j < 2; ++j) {
                int row = wn + j*32 + lc;
                bfr[j] = *(const bf16x8*)(Bs + row*64 + (((kk*2 + hi) ^ (row & 7)) << 3));
            }
            #pragma unroll
            for (int i = 0; i < 2; ++i)
                #pragma unroll
                for (int j = 0; j < 2; ++j)
                    acc[i][j] = __builtin_amdgcn_mfma_f32_32x32x16_bf16(af[i], bfr[j], acc[i][j], 0, 0, 0);
        }
        __syncthreads();
    }

    const int sect = n0 >> 10;
    float bq[2];
    #pragma unroll
    for (int j = 0; j < 2; ++j) bq[j] = bias[n0 + wn + j*32 + lc];

    if (sect < 2) {
        unsigned short* dst = sect ? kb : qb;
        const float sc = sect ? 1.0f : 0.125f * 1.44269504088896f;
        const int h = ((n0 & 1023) + wn) >> 6;
        #pragma unroll
        for (int i = 0; i < 2; ++i) {
            #pragma unroll
            for (int r = 0; r < 16; ++r) {
                int gm = m0 + wm + i*32 + (r & 3) + 8*(r >> 2) + 4*hi;
                int b  = gm >> 11, n = gm & 2047;
                size_t base = ((size_t)(b*NUM_HEADS + h) * NTOK + n) << 6;
                #pragma unroll
                for (int j = 0; j < 2; ++j) {
                    int d = j*32 + lc;
                    float val = acc[i][j][r] + bq[j];
                    float vp  = acc[i][j^1][r] + bq[j^1];
                    float rot = (j == 0) ? -vp : vp;
                    float c = rcos[n*64 + d], s = rsin[n*64 + d];
                    dst[base + d] = f2bf((val * c + rot * s) * sc);
                }
            }
        }
    } else {
        unsigned short (*vt)[136] = (unsigned short (*)[136])smem;
        __syncthreads();
        #pragma unroll
        for (int i = 0; i < 2; ++i)
            #pragma unroll
            for (int j = 0; j < 2; ++j)
                #pragma unroll
                for (int r = 0; r < 16; ++r) {
                    int row = wm + i*32 + (r & 3) + 8*(r >> 2) + 4*hi;
                    int c   = wn + j*32 + lc;
                    vt[c][row] = f2bf(acc[i][j][r] + bq[j]);
                }
        __syncthreads();
        const int b = m0 >> 11;
        const int nbase = m0 & 2047;
        #pragma unroll
        for (int it = 0; it < 8; ++it) {
            int c   = (tid >> 4) + it * 16;
            int sc2 = (n0 & 1023) + c;
            int hh  = sc2 >> 6, d = sc2 & 63;
            int nloc = (tid & 15) * 8;
            uint4 val = *(uint4*)&vt[c][nloc];
            *(uint4*)(vtb + ((size_t)(b*NUM_HEADS + hh) * HEAD_DIM + d) * NTOK + nbase + nloc) = val;
        }
    }
}

// ---------------- Kernel 2: flash attention (single-buffered K/V, 4 blocks/CU) ----------------
// 128 q/block, waves (qg,kvg) 2x2: each wave 64 q x 64 kv per 128-kv iter.
// K [0,16K) + V [16K,32K) single-buffered: stage -> barrier -> compute -> barrier.
// Epilogue addressing identical to R13 (verified): o2 slabs [0,32K), lsum at 32K.
// LDS 33.75KB -> 4 blocks/CU (occupancy experiment vs R13's 2). Grid (32 bh, 16 qt).
__global__ __launch_bounds__(256, 2) void k_attn(
    const unsigned short* __restrict__ qb, const unsigned short* __restrict__ kb,
    const unsigned short* __restrict__ vtb, unsigned short* __restrict__ attnb)
{
    __shared__ __align__(16) char sb[33792];

    const int tid  = threadIdx.x;
    const int lane = tid & 63;
    const int w    = tid >> 6;
    const int hi   = lane >> 5;
    const int lc   = lane & 31;
    const int qg   = w >> 1;
    const int kvg  = w & 1;
    const int q0   = blockIdx.y * 128;
    const int bh   = blockIdx.x;
    const int b    = bh >> 4, h = bh & 15;

    int koff[2][4];
    #pragma unroll
    for (int s = 0; s < 2; ++s)
        #pragma unroll
        for (int ks = 0; ks < 4; ++ks)
            koff[s][ks] = (64*kvg + 32*s + lc) * 128 + (((2*ks + hi) ^ (lc & 7)) << 4);
    int voff[2][4];
    #pragma unroll
    for (int dt = 0; dt < 2; ++dt)
        #pragma unroll
        for (int c4 = 0; c4 < 4; ++c4)
            voff[dt][c4] = 16384 + (32*dt + lc) * 256 + (((8*kvg + 2*c4 + hi) ^ (lc & 15)) << 4);

    const unsigned short* gk[4];
    const unsigned short* gv[4];
    char* dk[4]; char* dv[4];
    {
        const unsigned short* kbase = kb  + (size_t)bh * NTOK * 64;
        const unsigned short* vbase = vtb + (size_t)bh * HEAD_DIM * NTOK;
        #pragma unroll
        for (int it = 0; it < 4; ++it) {
            int p  = tid + it * 256;
            int kr = p >> 3;
            int kc = (p & 7) ^ (kr & 7);
            gk[it] = kbase + kr*64 + kc*8;
            dk[it] = sb + p*16;
            int vr = p >> 4;
            int vc = (p & 15) ^ (vr & 15);
            gv[it] = vbase + (size_t)vr*NTOK + vc*8;
            dv[it] = sb + 16384 + p*16;
        }
    }

    bf16x8 qa[2][4];
    #pragma unroll
    for (int qt = 0; qt < 2; ++qt) {
        size_t qrow = ((size_t)bh * NTOK + q0 + 64*qg + 32*qt + lc) * 64;
        #pragma unroll
        for (int ks = 0; ks < 4; ++ks)
            qa[qt][ks] = *(const bf16x8*)(qb + qrow + ks*16 + hi*8);
    }

    const f32x16 z16 = {0.f,0.f,0.f,0.f, 0.f,0.f,0.f,0.f, 0.f,0.f,0.f,0.f, 0.f,0.f,0.f,0.f};
    f32x16 o2[2][2];    // [qt][dt]
    o2[0][0] = z16; o2[0][1] = z16; o2[1][0] = z16; o2[1][1] = z16;
    float lsum0 = 0.f, lsum1 = 0.f;

#define PACKQT(SS, PB0, PB1)                                                     \
    {                                                                            \
        _Pragma("unroll")                                                        \
        for (int u = 0; u < 2; ++u) {                                            \
            unsigned int a0 = packbf(SS[8*u],     SS[8*u + 1]);                  \
            unsigned int b0 = packbf(SS[8*u + 4], SS[8*u + 5]);                  \
            unsigned int a1 = packbf(SS[8*u + 2], SS[8*u + 3]);                  \
            unsigned int b1 = packbf(SS[8*u + 6], SS[8*u + 7]);                  \
            plswap(a0, b0);                                                      \
            plswap(a1, b1);                                                      \
            union { unsigned int u4[4]; bf16x8 v; } pk;                          \
            pk.u4[0] = a0; pk.u4[1] = a1; pk.u4[2] = b0; pk.u4[3] = b1;          \
            if (u == 0) (PB0) = pk.v; else (PB1) = pk.v;                         \
        }                                                                        \
    }

    #pragma unroll 1
    for (int t = 0; t < NTOK/128; ++t) {
        // ---- stage tile t (single buffer) ----
        #pragma unroll
        for (int it = 0; it < 4; ++it) {
            gload16(gk[it], (unsigned short*)dk[it]);
            gload16(gv[it], (unsigned short*)dv[it]);
            gk[it] += 8192; gv[it] += 128;
        }
        __syncthreads();   // drain staging; K/V ready

        #pragma unroll
        for (int s = 0; s < 2; ++s) {
            bf16x8 kf[4];
            #pragma unroll
            for (int ks = 0; ks < 4; ++ks)
                kf[ks] = *(const bf16x8*)(sb + koff[s][ks]);
            __builtin_amdgcn_s_setprio(1);
            f32x16 S0 = __builtin_amdgcn_mfma_f32_32x32x16_bf16(kf[0], qa[0][0], z16, 0, 0, 0);
            f32x16 S1 = __builtin_amdgcn_mfma_f32_32x32x16_bf16(kf[0], qa[1][0], z16, 0, 0, 0);
            #pragma unroll
            for (int ks = 1; ks < 4; ++ks) {
                S0 = __builtin_amdgcn_mfma_f32_32x32x16_bf16(kf[ks], qa[0][ks], S0, 0, 0, 0);
                S1 = __builtin_amdgcn_mfma_f32_32x32x16_bf16(kf[ks], qa[1][ks], S1, 0, 0, 0);
            }
            __builtin_amdgcn_s_setprio(0);
            #pragma unroll
            for (int r = 0; r < 16; ++r) {
                S0[r] = __builtin_amdgcn_exp2f(S0[r]);
                S1[r] = __builtin_amdgcn_exp2f(S1[r]);
            }
            lsum0 += sum16v(S0);
            lsum1 += sum16v(S1);
            bf16x8 p00, p01, p10, p11;
            PACKQT(S0, p00, p01);
            PACKQT(S1, p10, p11);
            #pragma unroll
            for (int u = 0; u < 2; ++u) {
                bf16x8 pb0 = u ? p01 : p00;
                bf16x8 pb1 = u ? p11 : p10;
                #pragma unroll
                for (int dt = 0; dt < 2; ++dt) {
                    bf16x8 vf = *(const bf16x8*)(sb + voff[dt][2*s + u]);
                    __builtin_amdgcn_s_setprio(1);
                    o2[0][dt] = __builtin_amdgcn_mfma_f32_32x32x16_bf16(vf, pb0, o2[0][dt], 0, 0, 0);
                    o2[1][dt] = __builtin_amdgcn_mfma_f32_32x32x16_bf16(vf, pb1, o2[1][dt], 0, 0, 0);
                    __builtin_amdgcn_s_setprio(0);
                }
            }
        }
        __syncthreads();   // all reads done before next stage overwrites
    }
#undef PACKQT

    // ---- epilogue (R13-verified addressing): hi-half merge, then kvg merge ----
    lsum0 += __shfl_xor(lsum0, 32);
    lsum1 += __shfl_xor(lsum1, 32);

    if (kvg == 1) {
        char* base = sb + qg * 16384;
        #pragma unroll
        for (int qt = 0; qt < 2; ++qt)
            #pragma unroll
            for (int dt = 0; dt < 2; ++dt)
                #pragma unroll
                for (int part = 0; part < 4; ++part) {
                    f32x4 v4;
                    #pragma unroll
                    for (int v = 0; v < 4; ++v) v4[v] = o2[qt][dt][part*4 + v];
                    *(f32x4*)(base + ((qt*2 + dt)*4 + part)*1024 + lane*16) = v4;
                }
        *(float*)(sb + 32768 + (qg*2 + 0)*256 + lane*4) = lsum0;
        *(float*)(sb + 32768 + (qg*2 + 1)*256 + lane*4) = lsum1;
    }
    __syncthreads();
    if (kvg == 0) {
        char* base = sb + qg * 16384;
        float lp0 = *(const float*)(sb + 32768 + (qg*2 + 0)*256 + lane*4);
        float lp1 = *(const float*)(sb + 32768 + (qg*2 + 1)*256 + lane*4);
        const float inv0 = 1.0f / (lsum0 + lp0);
        const float inv1 = 1.0f / (lsum1 + lp1);
        #pragma unroll
        for (int qt = 0; qt < 2; ++qt) {
            const float inv = qt ? inv1 : inv0;
            int q = q0 + 64*qg + 32*qt + lc;
            size_t obase = ((size_t)(b*NTOK + q)) * DIM + h*HEAD_DIM;
            #pragma unroll
            for (int dt = 0; dt < 2; ++dt)
                #pragma unroll
                for (int c = 0; c < 4; ++c) {
                    f32x4 vp = *(const f32x4*)(base + ((qt*2 + dt)*4 + c)*1024 + lane*16);
                    union { unsigned short us[4]; uint2 u2; } pk4;
                    #pragma unroll
                    for (int v = 0; v < 4; ++v)
                        pk4.us[v] = f2bf((o2[qt][dt][c*4 + v] + vp[v]) * inv);
                    *(uint2*)(attnb + obase + dt*32 + 8*c + 4*hi) = pk4.u2;
                }
        }
    }
}

// ---------------- Kernel 3: output projection (32x32 MFMA, 128x64 tile) ----------------
__global__ __launch_bounds__(256) void k_proj(
    const unsigned short* __restrict__ a, const unsigned short* __restrict__ wb,
    const float* __restrict__ bias, float* __restrict__ out)
{
    __shared__ __align__(16) unsigned short As[8192];
    __shared__ __align__(16) unsigned short Bs[4096];

    const int tid  = threadIdx.x;
    const int lane = tid & 63;
    const int wid  = tid >> 6;
    const int lc   = lane & 31;
    const int hi   = lane >> 5;
    const int wm   = (wid & 1) * 64;
    const int wn   = (wid >> 1) * 32;
    const int m0   = blockIdx.y * 128;
    const int n0   = blockIdx.x * 64;

    const f32x16 z16 = {0.f,0.f,0.f,0.f, 0.f,0.f,0.f,0.f, 0.f,0.f,0.f,0.f, 0.f,0.f,0.f,0.f};
    f32x16 acc[2];
    acc[0] = z16; acc[1] = z16;

    for (int k0 = 0; k0 < DIM; k0 += 64) {
        #pragma unroll
        for (int it = 0; it < 4; ++it) {
            int p   = tid + it * 256;
            int row = p >> 3;
            int c   = (p & 7) ^ (row & 7);
            gload16(a + (size_t)(m0 + row) * DIM + k0 + c*8, As + p*8);
        }
        #pragma unroll
        for (int it = 0; it < 2; ++it) {
            int p   = tid + it * 256;
            int row = p >> 3;
            int c   = (p & 7) ^ (row & 7);
            gload16(wb + (size_t)(n0 + row) * DIM + k0 + c*8, Bs + p*8);
        }
        __syncthreads();
        #pragma unroll
        for (int kk = 0; kk < 4; ++kk) {
            bf16x8 af[2], bf;
            #pragma unroll
            for (int i = 0; i < 2; ++i) {
                int row = wm + i*32 + lc;
                af[i] = *(const bf16x8*)(As + row*64 + (((kk*2 + hi) ^ (row & 7)) << 3));
            }
            {
                int row = wn + lc;
                bf = *(const bf16x8*)(Bs + row*64 + (((kk*2 + hi) ^ (row & 7)) << 3));
            }
            #pragma unroll
            for (int i = 0; i < 2; ++i)
                acc[i] = __builtin_amdgcn_mfma_f32_32x32x16_bf16(af[i], bf, acc[i], 0, 0, 0);
        }
        __syncthreads();
    }

    #pragma unroll
    for (int i = 0; i < 2; ++i)
        #pragma unroll
        for (int r = 0; r < 16; ++r) {
            int row = m0 + wm + i*32 + (r & 3) + 8*(r >> 2) + 4*hi;
            int col = n0 + wn + lc;
            out[(size_t)row * DIM + col] = acc[i][r] + bias[col];
        }
}

extern "C" void kernel_launch(void* const* d_in, const int* in_sizes, int n_in,
                              void* d_out, int out_size, void* d_ws, size_t ws_size,
                              hipStream_t stream)
{
    const float* x      = (const float*)d_in[0];
    const float* rcos   = (const float*)d_in[1];
    const float* rsin   = (const float*)d_in[2];
    const float* qkv_w  = (const float*)d_in[3];
    const float* qkv_b  = (const float*)d_in[4];
    const float* proj_w = (const float*)d_in[5];
    const float* proj_b = (const float*)d_in[6];
    float* out = (float*)d_out;

    const size_t BUF = (size_t)2 * NUM_HEADS * NTOK * HEAD_DIM;
    unsigned short* qb    = (unsigned short*)d_ws;
    unsigned short* kb    = qb + BUF;
    unsigned short* vtb   = kb + BUF;
    unsigned short* attnb = vtb + BUF;
    unsigned short* xbf   = attnb + BUF;
    unsigned short* wqkvb = xbf + (size_t)MTOT * DIM;
    unsigned short* wprjb = wqkvb + (size_t)3 * DIM * DIM;

    const int n0 = MTOT * DIM, n1 = 3 * DIM * DIM, n2 = DIM * DIM;
    k_conv3<<<dim3((n0 + n1 + n2) / 2048), 256, 0, stream>>>(
        x, xbf, n0, qkv_w, wqkvb, n1, proj_w, wprjb, n2);

    k_gemm_qkv<<<dim3(24, 32), 256, 0, stream>>>(xbf, wqkvb, qkv_b, rcos, rsin, qb, kb, vtb);
    k_attn<<<dim3(32, NTOK/128), 256, 0, stream>>>(qb, kb, vtb, attnb);
    k_proj<<<dim3(16, 32), 256, 0, stream>>>(attnb, wprjb, proj_b, out);
}

// Round 16
// 114.944 us; speedup vs baseline: 1.0466x; 1.0466x over previous
//
#include <hip/hip_runtime.h>
#include <hip/hip_bf16.h>

#define NUM_HEADS 16
#define HEAD_DIM 64
#define DIM 1024
#define NTOK 2048
#define MTOT 4096

typedef __attribute__((ext_vector_type(8))) short bf16x8;
typedef __attribute__((ext_vector_type(4))) float f32x4;
typedef __attribute__((ext_vector_type(8))) float f32x8;
typedef __attribute__((ext_vector_type(16))) float f32x16;
typedef __attribute__((ext_vector_type(2))) unsigned int uint2v;

__device__ __forceinline__ unsigned short f2bf(float f) {
    union { __hip_bfloat16 h; unsigned short u; } c;
    c.h = __float2bfloat16(f);
    return c.u;
}

__device__ __forceinline__ unsigned int packbf(float lo, float hi) {
    union { unsigned short us[2]; unsigned int u; } p;
    p.us[0] = f2bf(lo); p.us[1] = f2bf(hi);
    return p.u;
}

__device__ __forceinline__ void plswap(unsigned int &a, unsigned int &b) {
#if __has_builtin(__builtin_amdgcn_permlane32_swap)
    uint2v r = __builtin_amdgcn_permlane32_swap(a, b, false, false);
    a = r[0]; b = r[1];
#else
    unsigned int pa = (unsigned int)__shfl_xor((int)a, 32);
    unsigned int pb = (unsigned int)__shfl_xor((int)b, 32);
    bool hi = (threadIdx.x & 32) != 0;
    unsigned int an = hi ? pb : a;
    unsigned int bn = hi ? b : pa;
    a = an; b = bn;
#endif
}

// vectorized 16-lane-local sum (enables v_pk_add_f32)
__device__ __forceinline__ float sum16v(f32x16 S) {
    f32x8 lo = __builtin_shufflevector(S, S, 0, 1, 2, 3, 4, 5, 6, 7);
    f32x8 hi = __builtin_shufflevector(S, S, 8, 9, 10, 11, 12, 13, 14, 15);
    f32x8 s8 = lo + hi;
    f32x4 a4 = __builtin_shufflevector(s8, s8, 0, 1, 2, 3) +
               __builtin_shufflevector(s8, s8, 4, 5, 6, 7);
    return (a4[0] + a4[1]) + (a4[2] + a4[3]);
}

__device__ __forceinline__ void gload16(const unsigned short* g, unsigned short* l) {
    __builtin_amdgcn_global_load_lds(
        (const __attribute__((address_space(1))) void*)g,
        (__attribute__((address_space(3))) void*)l, 16, 0, 0);
}

// ---------------- Kernel 0: fused fp32 -> bf16 convert ----------------
__global__ __launch_bounds__(256) void k_conv3(
    const float* __restrict__ s0, unsigned short* __restrict__ d0, int n0,
    const float* __restrict__ s1, unsigned short* __restrict__ d1, int n1,
    const float* __restrict__ s2, unsigned short* __restrict__ d2, int n2)
{
    int blk = blockIdx.x;
    int b0 = n0 >> 11, b1 = n1 >> 11;
    const float* s; unsigned short* d; int i;
    if (blk < b0)            { s = s0; d = d0; i = blk; }
    else if (blk < b0 + b1)  { s = s1; d = d1; i = blk - b0; }
    else                     { s = s2; d = d2; i = blk - b0 - b1; }
    int idx = (i * 256 + threadIdx.x) * 8;
    float4 a = *(const float4*)(s + idx);
    float4 b = *(const float4*)(s + idx + 4);
    union { unsigned short us[8]; uint4 u4; } p;
    p.us[0] = f2bf(a.x); p.us[1] = f2bf(a.y); p.us[2] = f2bf(a.z); p.us[3] = f2bf(a.w);
    p.us[4] = f2bf(b.x); p.us[5] = f2bf(b.y); p.us[6] = f2bf(b.z); p.us[7] = f2bf(b.w);
    *(uint4*)(d + idx) = p.u4;
}

// ---------------- Kernel 1: QKV GEMM (32x32 MFMA) + bias + RoPE + layout ----------------
__global__ __launch_bounds__(256) void k_gemm_qkv(
    const unsigned short* __restrict__ xb, const unsigned short* __restrict__ wb,
    const float* __restrict__ bias, const float* __restrict__ rcos,
    const float* __restrict__ rsin,
    unsigned short* __restrict__ qb, unsigned short* __restrict__ kb,
    unsigned short* __restrict__ vtb)
{
    __shared__ __align__(16) unsigned char smem[34816];
    unsigned short* As = (unsigned short*)smem;
    unsigned short* Bs = (unsigned short*)(smem + 16384);

    const int tid  = threadIdx.x;
    const int lane = tid & 63;
    const int wid  = tid >> 6;
    const int lc   = lane & 31;
    const int hi   = lane >> 5;
    const int wm   = (wid >> 1) * 64;
    const int wn   = (wid & 1) * 64;
    const int m0   = blockIdx.y * 128;
    const int n0   = blockIdx.x * 128;

    const f32x16 z16 = {0.f,0.f,0.f,0.f, 0.f,0.f,0.f,0.f, 0.f,0.f,0.f,0.f, 0.f,0.f,0.f,0.f};
    f32x16 acc[2][2];
    acc[0][0] = z16; acc[0][1] = z16; acc[1][0] = z16; acc[1][1] = z16;

    for (int k0 = 0; k0 < DIM; k0 += 64) {
        #pragma unroll
        for (int it = 0; it < 4; ++it) {
            int p   = tid + it * 256;
            int row = p >> 3;
            int c   = (p & 7) ^ (row & 7);
            gload16(xb + (size_t)(m0 + row) * DIM + k0 + c*8, As + p*8);
            gload16(wb + (size_t)(n0 + row) * DIM + k0 + c*8, Bs + p*8);
        }
        __syncthreads();
        #pragma unroll
        for (int kk = 0; kk < 4; ++kk) {
            bf16x8 af[2], bfr[2];
            #pragma unroll
            for (int i = 0; i < 2; ++i) {
                int row = wm + i*32 + lc;
                af[i] = *(const bf16x8*)(As + row*64 + (((kk*2 + hi) ^ (row & 7)) << 3));
            }
            #pragma unroll
            for (int j = 0; j < 2; ++j) {
                int row = wn + j*32 + lc;
                bfr[j] = *(const bf16x8*)(Bs + row*64 + (((kk*2 + hi) ^ (row & 7)) << 3));
            }
            #pragma unroll
            for (int i = 0; i < 2; ++i)
                #pragma unroll
                for (int j = 0; j < 2; ++j)
                    acc[i][j] = __builtin_amdgcn_mfma_f32_32x32x16_bf16(af[i], bfr[j], acc[i][j], 0, 0, 0);
        }
        __syncthreads();
    }

    const int sect = n0 >> 10;
    float bq[2];
    #pragma unroll
    for (int j = 0; j < 2; ++j) bq[j] = bias[n0 + wn + j*32 + lc];

    if (sect < 2) {
        unsigned short* dst = sect ? kb : qb;
        const float sc = sect ? 1.0f : 0.125f * 1.44269504088896f;
        const int h = ((n0 & 1023) + wn) >> 6;
        #pragma unroll
        for (int i = 0; i < 2; ++i) {
            #pragma unroll
            for (int r = 0; r < 16; ++r) {
                int gm = m0 + wm + i*32 + (r & 3) + 8*(r >> 2) + 4*hi;
                int b  = gm >> 11, n = gm & 2047;
                size_t base = ((size_t)(b*NUM_HEADS + h) * NTOK + n) << 6;
                #pragma unroll
                for (int j = 0; j < 2; ++j) {
                    int d = j*32 + lc;
                    float val = acc[i][j][r] + bq[j];
                    float vp  = acc[i][j^1][r] + bq[j^1];
                    float rot = (j == 0) ? -vp : vp;
                    float c = rcos[n*64 + d], s = rsin[n*64 + d];
                    dst[base + d] = f2bf((val * c + rot * s) * sc);
                }
            }
        }
    } else {
        unsigned short (*vt)[136] = (unsigned short (*)[136])smem;
        __syncthreads();
        #pragma unroll
        for (int i = 0; i < 2; ++i)
            #pragma unroll
            for (int j = 0; j < 2; ++j)
                #pragma unroll
                for (int r = 0; r < 16; ++r) {
                    int row = wm + i*32 + (r & 3) + 8*(r >> 2) + 4*hi;
                    int c   = wn + j*32 + lc;
                    vt[c][row] = f2bf(acc[i][j][r] + bq[j]);
                }
        __syncthreads();
        const int b = m0 >> 11;
        const int nbase = m0 & 2047;
        #pragma unroll
        for (int it = 0; it < 8; ++it) {
            int c   = (tid >> 4) + it * 16;
            int sc2 = (n0 & 1023) + c;
            int hh  = sc2 >> 6, d = sc2 & 63;
            int nloc = (tid & 15) * 8;
            uint4 val = *(uint4*)&vt[c][nloc];
            *(uint4*)(vtb + ((size_t)(b*NUM_HEADS + hh) * HEAD_DIM + d) * NTOK + nbase + nloc) = val;
        }
    }
}

// ---------------- Kernel 2: flash attention (R13 config: 2x2 split, no-max, dbuf) ----------------
// 128 q/block, waves (qg,kvg) 2x2: each wave 64 q x 64 kv per 128-kv iter.
// K+V staged in 64KB swizzled LDS (double-buffered), no-max softmax,
// vectorized in-lane lsum, kvg-merge via LDS epilogue. Grid (32 bh, 16 qt) = T1.
__global__ __launch_bounds__(256, 2) void k_attn(
    const unsigned short* __restrict__ qb, const unsigned short* __restrict__ kb,
    const unsigned short* __restrict__ vtb, unsigned short* __restrict__ attnb)
{
    __shared__ __align__(16) char sb[65536];

    const int tid  = threadIdx.x;
    const int lane = tid & 63;
    const int w    = tid >> 6;
    const int hi   = lane >> 5;
    const int lc   = lane & 31;
    const int qg   = w >> 1;
    const int kvg  = w & 1;
    const int q0   = blockIdx.y * 128;
    const int bh   = blockIdx.x;
    const int b    = bh >> 4, h = bh & 15;

    int koff[2][4];
    #pragma unroll
    for (int s = 0; s < 2; ++s)
        #pragma unroll
        for (int ks = 0; ks < 4; ++ks)
            koff[s][ks] = (64*kvg + 32*s + lc) * 128 + (((2*ks + hi) ^ (lc & 7)) << 4);
    int voff[2][4];
    #pragma unroll
    for (int dt = 0; dt < 2; ++dt)
        #pragma unroll
        for (int c4 = 0; c4 < 4; ++c4)
            voff[dt][c4] = 32768 + (32*dt + lc) * 256 + (((8*kvg + 2*c4 + hi) ^ (lc & 15)) << 4);

    const unsigned short* gk[4];
    const unsigned short* gv[4];
    char* dk[4]; char* dv[4];
    {
        const unsigned short* kbase = kb  + (size_t)bh * NTOK * 64;
        const unsigned short* vbase = vtb + (size_t)bh * HEAD_DIM * NTOK;
        #pragma unroll
        for (int it = 0; it < 4; ++it) {
            int p  = tid + it * 256;
            int kr = p >> 3;
            int kc = (p & 7) ^ (kr & 7);
            gk[it] = kbase + kr*64 + kc*8;
            dk[it] = sb + p*16;
            int vr = p >> 4;
            int vc = (p & 15) ^ (vr & 15);
            gv[it] = vbase + (size_t)vr*NTOK + vc*8;
            dv[it] = sb + 32768 + p*16;
        }
    }

    bf16x8 qa[2][4];
    #pragma unroll
    for (int qt = 0; qt < 2; ++qt) {
        size_t qrow = ((size_t)bh * NTOK + q0 + 64*qg + 32*qt + lc) * 64;
        #pragma unroll
        for (int ks = 0; ks < 4; ++ks)
            qa[qt][ks] = *(const bf16x8*)(qb + qrow + ks*16 + hi*8);
    }

    const f32x16 z16 = {0.f,0.f,0.f,0.f, 0.f,0.f,0.f,0.f, 0.f,0.f,0.f,0.f, 0.f,0.f,0.f,0.f};
    f32x16 o2[2][2];    // [qt][dt]
    o2[0][0] = z16; o2[0][1] = z16; o2[1][0] = z16; o2[1][1] = z16;
    float lsum0 = 0.f, lsum1 = 0.f;

    #pragma unroll
    for (int it = 0; it < 4; ++it) {
        gload16(gk[it], (unsigned short*)dk[it]);
        gload16(gv[it], (unsigned short*)dv[it]);
        gk[it] += 8192; gv[it] += 128;
    }
    __syncthreads();

#define PACKQT(SS, PB0, PB1)                                                     \
    {                                                                            \
        _Pragma("unroll")                                                        \
        for (int u = 0; u < 2; ++u) {                                            \
            unsigned int a0 = packbf(SS[8*u],     SS[8*u + 1]);                  \
            unsigned int b0 = packbf(SS[8*u + 4], SS[8*u + 5]);                  \
            unsigned int a1 = packbf(SS[8*u + 2], SS[8*u + 3]);                  \
            unsigned int b1 = packbf(SS[8*u + 6], SS[8*u + 7]);                  \
            plswap(a0, b0);                                                      \
            plswap(a1, b1);                                                      \
            union { unsigned int u4[4]; bf16x8 v; } pk;                          \
            pk.u4[0] = a0; pk.u4[1] = a1; pk.u4[2] = b0; pk.u4[3] = b1;          \
            if (u == 0) (PB0) = pk.v; else (PB1) = pk.v;                         \
        }                                                                        \
    }

#define ATTN_ITER(X, DO_STAGE)                                                   \
    {                                                                            \
        if (DO_STAGE) {                                                          \
            _Pragma("unroll")                                                    \
            for (int it = 0; it < 4; ++it) {                                     \
                gload16(gk[it], (unsigned short*)(dk[it] + ((X) ^ 16384)));      \
                gload16(gv[it], (unsigned short*)(dv[it] + ((X) ^ 16384)));      \
                gk[it] += 8192; gv[it] += 128;                                   \
            }                                                                    \
        }                                                                        \
        _Pragma("unroll")                                                        \
        for (int s = 0; s < 2; ++s) {                                            \
            bf16x8 kf[4];                                                        \
            _Pragma("unroll")                                                    \
            for (int ks = 0; ks < 4; ++ks)                                       \
                kf[ks] = *(const bf16x8*)(sb + (X) + koff[s][ks]);               \
            __builtin_amdgcn_s_setprio(1);                                       \
            f32x16 S0 = __builtin_amdgcn_mfma_f32_32x32x16_bf16(kf[0], qa[0][0], z16, 0, 0, 0); \
            f32x16 S1 = __builtin_amdgcn_mfma_f32_32x32x16_bf16(kf[0], qa[1][0], z16, 0, 0, 0); \
            _Pragma("unroll")                                                    \
            for (int ks = 1; ks < 4; ++ks) {                                     \
                S0 = __builtin_amdgcn_mfma_f32_32x32x16_bf16(kf[ks], qa[0][ks], S0, 0, 0, 0); \
                S1 = __builtin_amdgcn_mfma_f32_32x32x16_bf16(kf[ks], qa[1][ks], S1, 0, 0, 0); \
            }                                                                    \
            __builtin_amdgcn_s_setprio(0);                                       \
            _Pragma("unroll")                                                    \
            for (int r = 0; r < 16; ++r) {                                       \
                S0[r] = __builtin_amdgcn_exp2f(S0[r]);                           \
                S1[r] = __builtin_amdgcn_exp2f(S1[r]);                           \
            }                                                                    \
            lsum0 += sum16v(S0);                                                 \
            lsum1 += sum16v(S1);                                                 \
            bf16x8 p00, p01, p10, p11;                                           \
            PACKQT(S0, p00, p01);                                                \
            PACKQT(S1, p10, p11);                                                \
            _Pragma("unroll")                                                    \
            for (int u = 0; u < 2; ++u) {                                        \
                bf16x8 pb0 = u ? p01 : p00;                                      \
                bf16x8 pb1 = u ? p11 : p10;                                      \
                _Pragma("unroll")                                                \
                for (int dt = 0; dt < 2; ++dt) {                                 \
                    bf16x8 vf = *(const bf16x8*)(sb + (X) + voff[dt][2*s + u]);  \
                    __builtin_amdgcn_s_setprio(1);                               \
                    o2[0][dt] = __builtin_amdgcn_mfma_f32_32x32x16_bf16(vf, pb0, o2[0][dt], 0, 0, 0); \
                    o2[1][dt] = __builtin_amdgcn_mfma_f32_32x32x16_bf16(vf, pb1, o2[1][dt], 0, 0, 0); \
                    __builtin_amdgcn_s_setprio(0);                               \
                }                                                                \
            }                                                                    \
        }                                                                        \
        __syncthreads();                                                         \
    }

    #pragma unroll 1
    for (int tt = 0; tt < NTOK/128; tt += 2) {
        ATTN_ITER(0,     true);
        ATTN_ITER(16384, (tt + 2 < NTOK/128));
    }
#undef ATTN_ITER
#undef PACKQT

    // ---- epilogue: hi-half merge, then kvg merge via LDS (pure add) ----
    lsum0 += __shfl_xor(lsum0, 32);
    lsum1 += __shfl_xor(lsum1, 32);

    if (kvg == 1) {
        char* base = sb + qg * 16384;
        #pragma unroll
        for (int qt = 0; qt < 2; ++qt)
            #pragma unroll
            for (int dt = 0; dt < 2; ++dt)
                #pragma unroll
                for (int part = 0; part < 4; ++part) {
                    f32x4 v4;
                    #pragma unroll
                    for (int v = 0; v < 4; ++v) v4[v] = o2[qt][dt][part*4 + v];
                    *(f32x4*)(base + ((qt*2 + dt)*4 + part)*1024 + lane*16) = v4;
                }
        *(float*)(sb + 32768 + (qg*2 + 0)*256 + lane*4) = lsum0;
        *(float*)(sb + 32768 + (qg*2 + 1)*256 + lane*4) = lsum1;
    }
    __syncthreads();
    if (kvg == 0) {
        char* base = sb + qg * 16384;
        float lp0 = *(const float*)(sb + 32768 + (qg*2 + 0)*256 + lane*4);
        float lp1 = *(const float*)(sb + 32768 + (qg*2 + 1)*256 + lane*4);
        const float inv0 = 1.0f / (lsum0 + lp0);
        const float inv1 = 1.0f / (lsum1 + lp1);
        #pragma unroll
        for (int qt = 0; qt < 2; ++qt) {
            const float inv = qt ? inv1 : inv0;
            int q = q0 + 64*qg + 32*qt + lc;
            size_t obase = ((size_t)(b*NTOK + q)) * DIM + h*HEAD_DIM;
            #pragma unroll
            for (int dt = 0; dt < 2; ++dt)
                #pragma unroll
                for (int c = 0; c < 4; ++c) {
                    f32x4 vp = *(const f32x4*)(base + ((qt*2 + dt)*4 + c)*1024 + lane*16);
                    union { unsigned short us[4]; uint2 u2; } pk4;
                    #pragma unroll
                    for (int v = 0; v < 4; ++v)
                        pk4.us[v] = f2bf((o2[qt][dt][c*4 + v] + vp[v]) * inv);
                    *(uint2*)(attnb + obase + dt*32 + 8*c + 4*hi) = pk4.u2;
                }
        }
    }
}

// ---------------- Kernel 3: output projection (32x32 MFMA, 128x64 tile) ----------------
__global__ __launch_bounds__(256) void k_proj(
    const unsigned short* __restrict__ a, const unsigned short* __restrict__ wb,
    const float* __restrict__ bias, float* __restrict__ out)
{
    __shared__ __align__(16) unsigned short As[8192];
    __shared__ __align__(16) unsigned short Bs[4096];

    const int tid  = threadIdx.x;
    const int lane = tid & 63;
    const int wid  = tid >> 6;
    const int lc   = lane & 31;
    const int hi   = lane >> 5;
    const int wm   = (wid & 1) * 64;
    const int wn   = (wid >> 1) * 32;
    const int m0   = blockIdx.y * 128;
    const int n0   = blockIdx.x * 64;

    const f32x16 z16 = {0.f,0.f,0.f,0.f, 0.f,0.f,0.f,0.f, 0.f,0.f,0.f,0.f, 0.f,0.f,0.f,0.f};
    f32x16 acc[2];
    acc[0] = z16; acc[1] = z16;

    for (int k0 = 0; k0 < DIM; k0 += 64) {
        #pragma unroll
        for (int it = 0; it < 4; ++it) {
            int p   = tid + it * 256;
            int row = p >> 3;
            int c   = (p & 7) ^ (row & 7);
            gload16(a + (size_t)(m0 + row) * DIM + k0 + c*8, As + p*8);
        }
        #pragma unroll
        for (int it = 0; it < 2; ++it) {
            int p   = tid + it * 256;
            int row = p >> 3;
            int c   = (p & 7) ^ (row & 7);
            gload16(wb + (size_t)(n0 + row) * DIM + k0 + c*8, Bs + p*8);
        }
        __syncthreads();
        #pragma unroll
        for (int kk = 0; kk < 4; ++kk) {
            bf16x8 af[2], bf;
            #pragma unroll
            for (int i = 0; i < 2; ++i) {
                int row = wm + i*32 + lc;
                af[i] = *(const bf16x8*)(As + row*64 + (((kk*2 + hi) ^ (row & 7)) << 3));
            }
            {
                int row = wn + lc;
                bf = *(const bf16x8*)(Bs + row*64 + (((kk*2 + hi) ^ (row & 7)) << 3));
            }
            #pragma unroll
            for (int i = 0; i < 2; ++i)
                acc[i] = __builtin_amdgcn_mfma_f32_32x32x16_bf16(af[i], bf, acc[i], 0, 0, 0);
        }
        __syncthreads();
    }

    #pragma unroll
    for (int i = 0; i < 2; ++i)
        #pragma unroll
        for (int r = 0; r < 16; ++r) {
            int row = m0 + wm + i*32 + (r & 3) + 8*(r >> 2) + 4*hi;
            int col = n0 + wn + lc;
            out[(size_t)row * DIM + col] = acc[i][r] + bias[col];
        }
}

extern "C" void kernel_launch(void* const* d_in, const int* in_sizes, int n_in,
                              void* d_out, int out_size, void* d_ws, size_t ws_size,
                              hipStream_t stream)
{
    const float* x      = (const float*)d_in[0];
    const float* rcos   = (const float*)d_in[1];
    const float* rsin   = (const float*)d_in[2];
    const float* qkv_w  = (const float*)d_in[3];
    const float* qkv_b  = (const float*)d_in[4];
    const float* proj_w = (const float*)d_in[5];
    const float* proj_b = (const float*)d_in[6];
    float* out = (float*)d_out;

    const size_t BUF = (size_t)2 * NUM_HEADS * NTOK * HEAD_DIM;
    unsigned short* qb    = (unsigned short*)d_ws;
    unsigned short* kb    = qb + BUF;
    unsigned short* vtb   = kb + BUF;
    unsigned short* attnb = vtb + BUF;
    unsigned short* xbf   = attnb + BUF;
    unsigned short* wqkvb = xbf + (size_t)MTOT * DIM;
    unsigned short* wprjb = wqkvb + (size_t)3 * DIM * DIM;

    const int n0 = MTOT * DIM, n1 = 3 * DIM * DIM, n2 = DIM * DIM;
    k_conv3<<<dim3((n0 + n1 + n2) / 2048), 256, 0, stream>>>(
        x, xbf, n0, qkv_w, wqkvb, n1, proj_w, wprjb, n2);

    k_gemm_qkv<<<dim3(24, 32), 256, 0, stream>>>(xbf, wqkvb, qkv_b, rcos, rsin, qb, kb, vtb);
    k_attn<<<dim3(32, NTOK/128), 256, 0, stream>>>(qb, kb, vtb, attnb);
    k_proj<<<dim3(16, 32), 256, 0, stream>>>(attnb, wprjb, proj_b, out);
}